// Round 6
// baseline (383.487 us; speedup 1.0000x reference)
//
#include <hip/hip_runtime.h>
#include <math.h>

#define NODE_DIM 64
#define EDGE_DIM 16
#define HEADS 4
#define CAP 64
#define CAP_LDS 48
#define NEG_SLOPE 0.2f
#define BN_EPS 1e-5f

typedef unsigned short ushort_t;

__device__ __forceinline__ float wave_max64(float v) {
#pragma unroll
    for (int o = 32; o; o >>= 1) v = fmaxf(v, __shfl_xor(v, o, 64));
    return v;
}
__device__ __forceinline__ float wave_sum64(float v) {
#pragma unroll
    for (int o = 32; o; o >>= 1) v += __shfl_xor(v, o, 64);
    return v;
}
__device__ __forceinline__ float lrelu(float s) {
    return fmaxf(s, 0.f) + NEG_SLOPE * fminf(s, 0.f);
}
__device__ __forceinline__ ushort_t f2bf(float f) {  // round-to-nearest-even
    unsigned int b = __float_as_uint(f);
    b += 0x7FFFu + ((b >> 16) & 1u);
    return (ushort_t)(b >> 16);
}
__device__ __forceinline__ float bf2f(ushort_t u) {
    return __uint_as_float(((unsigned int)u) << 16);
}

// K1: xr = x@Wr + br (f32) ; xlbf = bf16(x@Wl + bl). One wave per row.
__global__ __launch_bounds__(256) void k_transform(
    const float* __restrict__ x, const float* __restrict__ Wl,
    const float* __restrict__ bl, const float* __restrict__ Wr,
    const float* __restrict__ br, ushort_t* __restrict__ xlbf,
    float* __restrict__ xr, int n)
{
    __shared__ float sWl[NODE_DIM * NODE_DIM];
    __shared__ float sWr[NODE_DIM * NODE_DIM];
    for (int i = threadIdx.x; i < NODE_DIM * NODE_DIM; i += 256) {
        sWl[i] = Wl[i];
        sWr[i] = Wr[i];
    }
    __syncthreads();
    int lane = threadIdx.x & 63;
    int wid = threadIdx.x >> 6;
    for (int row = blockIdx.x * 4 + wid; row < n; row += gridDim.x * 4) {
        float xown = x[(size_t)row * NODE_DIM + lane];
        float al = bl[lane], ar = br[lane];
#pragma unroll
        for (int k = 0; k < NODE_DIM; k++) {
            float xv = __shfl(xown, k, 64);
            al = fmaf(xv, sWl[k * 64 + lane], al);
            ar = fmaf(xv, sWr[k * 64 + lane], ar);
        }
        xlbf[(size_t)row * NODE_DIM + lane] = f2bf(al);
        xr[(size_t)row * NODE_DIM + lane] = ar;
    }
}

// K2a: histogram of dst
__global__ __launch_bounds__(256) void k_count(
    const int* __restrict__ ei, int* __restrict__ counts, int E)
{
    int e = blockIdx.x * 256 + threadIdx.x;
    if (e >= E) return;
    atomicAdd(&counts[ei[E + e]], 1);
}

// K2b: exclusive scan of counts -> offs (single block)
__global__ __launch_bounds__(256) void k_scan(
    const int* __restrict__ counts, int* __restrict__ offs, int n)
{
    __shared__ int ssum[256];
    int tid = threadIdx.x;
    int chunk = (n + 255) / 256;
    int lo = tid * chunk;
    int hi = lo + chunk; if (hi > n) hi = n;
    int s = 0;
    for (int j = lo; j < hi; j++) s += counts[j];
    ssum[tid] = s;
    __syncthreads();
    for (int d = 1; d < 256; d <<= 1) {
        int v = (tid >= d) ? ssum[tid - d] : 0;
        __syncthreads();
        ssum[tid] += v;
        __syncthreads();
    }
    int base = (tid == 0) ? 0 : ssum[tid - 1];
    for (int j = lo; j < hi; j++) { offs[j] = base; base += counts[j]; }
}

// K2c: CSR bucket-sort: slots[pos]=src, eattr_s[pos]=eattr row (64B)
__global__ __launch_bounds__(256) void k_scatter(
    const int* __restrict__ ei, const float4* __restrict__ eattr4,
    const int* __restrict__ offs, int* __restrict__ cursors,
    int* __restrict__ slots, float4* __restrict__ eattr_s4, int E)
{
    int e = blockIdx.x * 256 + threadIdx.x;
    if (e >= E) return;
    int src = ei[e];
    int dst = ei[E + e];
    float4 r0 = eattr4[(size_t)e * 4 + 0];
    float4 r1 = eattr4[(size_t)e * 4 + 1];
    float4 r2 = eattr4[(size_t)e * 4 + 2];
    float4 r3 = eattr4[(size_t)e * 4 + 3];
    int pos = offs[dst] + atomicAdd(&cursors[dst], 1);
    slots[pos] = src;
    eattr_s4[(size_t)pos * 4 + 0] = r0;
    eattr_s4[(size_t)pos * 4 + 1] = r1;
    eattr_s4[(size_t)pos * 4 + 2] = r2;
    eattr_s4[(size_t)pos * 4 + 3] = r3;
}

struct Pipe {
    float4 e0, e1, e2, e3;
    ushort_t xu;
};

// K3 (fused): 4 nodes/block, one wave each. No __syncthreads (per-wave LDS).
// Phase A: lane = channel, 4-deep pipelined edge loop; eattr from CSR-sorted
// stream (wave-uniform sequential); xl stash -> LDS (t<48).
// Phase B: lane = edge, wave softmax. Phase C: lane = channel, LDS aggregate.
__global__ __launch_bounds__(256) void k_fused(
    const int* __restrict__ slots, const int* __restrict__ offs,
    const int* __restrict__ counts, const float* __restrict__ eattr_s,
    const float* __restrict__ We, const float* __restrict__ att,
    const ushort_t* __restrict__ xlbf, const float* __restrict__ xr,
    const float* __restrict__ bias, float* __restrict__ out, int n)
{
    __shared__ ushort_t sxl[4][CAP_LDS * 64];  // per-wave bf16 xl rows
    __shared__ float slog[4][CAP * 4];         // per-wave logits [t][head]
    __shared__ float salpha[4][CAP * 4];       // per-wave alpha  [t][head]

    int wid = threadIdx.x >> 6;
    int lane = threadIdx.x & 63;
    int i = blockIdx.x * 4 + wid;
    if (i >= n) return;

    int deg = counts[i];
    if (deg > CAP) deg = CAP;
    int base = offs[i];
    bool act = (lane < deg);

    int se_x = act ? slots[base + lane] : 0;

    // per-lane channel constants
    float xr_c = xr[(size_t)i * NODE_DIM + lane];
    float att_c = att[lane];
    float we_c[EDGE_DIM];
#pragma unroll
    for (int k = 0; k < EDGE_DIM; k++) we_c[k] = We[k * NODE_DIM + lane];

    int h = lane >> 4;
    ushort_t* sxlW = sxl[wid];
    float* slogW = slog[wid];
    float* salW = salpha[wid];

    auto LOADP = [&](int T, Pipe& P) {
        const float4* e4 = (const float4*)(eattr_s + ((size_t)base + T) * EDGE_DIM);
        P.e0 = e4[0]; P.e1 = e4[1]; P.e2 = e4[2]; P.e3 = e4[3];
        int src_t = __builtin_amdgcn_readlane(se_x, T);
        P.xu = xlbf[(size_t)src_t * NODE_DIM + lane];
    };
    auto COMP = [&](int T, const Pipe& P) {
        float p0 = 0.f, p1 = 0.f;
        p0 = fmaf(P.e0.x, we_c[0], p0);  p1 = fmaf(P.e0.y, we_c[1], p1);
        p0 = fmaf(P.e0.z, we_c[2], p0);  p1 = fmaf(P.e0.w, we_c[3], p1);
        p0 = fmaf(P.e1.x, we_c[4], p0);  p1 = fmaf(P.e1.y, we_c[5], p1);
        p0 = fmaf(P.e1.z, we_c[6], p0);  p1 = fmaf(P.e1.w, we_c[7], p1);
        p0 = fmaf(P.e2.x, we_c[8], p0);  p1 = fmaf(P.e2.y, we_c[9], p1);
        p0 = fmaf(P.e2.z, we_c[10], p0); p1 = fmaf(P.e2.w, we_c[11], p1);
        p0 = fmaf(P.e3.x, we_c[12], p0); p1 = fmaf(P.e3.y, we_c[13], p1);
        p0 = fmaf(P.e3.z, we_c[14], p0); p1 = fmaf(P.e3.w, we_c[15], p1);
        float s = bf2f(P.xu) + xr_c + (p0 + p1);
        float g = lrelu(s) * att_c;
        g += __shfl_xor(g, 1, 64);
        g += __shfl_xor(g, 2, 64);
        g += __shfl_xor(g, 4, 64);
        g += __shfl_xor(g, 8, 64);
        if (T < CAP_LDS) sxlW[T * 64 + lane] = P.xu;
        if ((lane & 15) == 0) slogW[T * 4 + h] = g;
    };

    // ---- Phase A: 4-deep software pipeline over edges ----
    if (deg > 0) {
        Pipe PA, PB, PC, PD;
        LOADP(0, PA);
        if (deg > 1) LOADP(1, PB);
        if (deg > 2) LOADP(2, PC);
        int t = 0;
        for (;;) {
            if (t + 3 < deg) LOADP(t + 3, PD);
            COMP(t, PA); if (++t >= deg) break;
            if (t + 3 < deg) LOADP(t + 3, PA);
            COMP(t, PB); if (++t >= deg) break;
            if (t + 3 < deg) LOADP(t + 3, PB);
            COMP(t, PC); if (++t >= deg) break;
            if (t + 3 < deg) LOADP(t + 3, PC);
            COMP(t, PD); if (++t >= deg) break;
        }
    }

    // ---- Phase B: lane = edge; wave softmax over deg lanes, 4 heads ----
    float4 lg = ((const float4*)slogW)[lane];
    float l0 = act ? lg.x : -1e30f;
    float l1 = act ? lg.y : -1e30f;
    float l2 = act ? lg.z : -1e30f;
    float l3 = act ? lg.w : -1e30f;
    float m0 = wave_max64(l0), m1 = wave_max64(l1);
    float m2 = wave_max64(l2), m3 = wave_max64(l3);
    float e0 = act ? __expf(l0 - m0) : 0.f;
    float e1 = act ? __expf(l1 - m1) : 0.f;
    float e2 = act ? __expf(l2 - m2) : 0.f;
    float e3 = act ? __expf(l3 - m3) : 0.f;
    float s0 = wave_sum64(e0), s1 = wave_sum64(e1);
    float s2 = wave_sum64(e2), s3 = wave_sum64(e3);
    ((float4*)salW)[lane] = make_float4(
        e0 / (s0 + 1e-16f), e1 / (s1 + 1e-16f),
        e2 / (s2 + 1e-16f), e3 / (s3 + 1e-16f));

    // ---- Phase C: lane = channel; aggregate from LDS stash ----
    float acc0 = 0.f, acc1 = 0.f;
    int dl = deg < CAP_LDS ? deg : CAP_LDS;
    int t = 0;
    for (; t + 1 < dl; t += 2) {
        acc0 = fmaf(salW[t * 4 + h], bf2f(sxlW[t * 64 + lane]), acc0);
        acc1 = fmaf(salW[(t + 1) * 4 + h], bf2f(sxlW[(t + 1) * 64 + lane]), acc1);
    }
    if (t < dl) acc0 = fmaf(salW[t * 4 + h], bf2f(sxlW[t * 64 + lane]), acc0);
    // rare tail (deg > 48): global re-gather
    for (int u = dl; u < deg; u++) {
        int src_t = __builtin_amdgcn_readlane(se_x, u);
        acc0 = fmaf(salW[u * 4 + h],
                    bf2f(xlbf[(size_t)src_t * NODE_DIM + lane]), acc0);
    }
    out[(size_t)i * NODE_DIM + lane] = acc0 + acc1 + bias[lane];
}

// K4: column sums / sumsq for BatchNorm
__global__ __launch_bounds__(256) void k_bnstat(
    const float* __restrict__ out, float* __restrict__ stats, int n)
{
    __shared__ float sbuf[256];
    int col = threadIdx.x & 63;
    int rgrp = threadIdx.x >> 6;
    float s = 0.f, q = 0.f;
    for (int row = blockIdx.x * 4 + rgrp; row < n; row += gridDim.x * 4) {
        float v = out[(size_t)row * 64 + col];
        s += v;
        q = fmaf(v, v, q);
    }
    sbuf[threadIdx.x] = s;
    __syncthreads();
    if (threadIdx.x < 64) {
        s = sbuf[threadIdx.x] + sbuf[threadIdx.x + 64] +
            sbuf[threadIdx.x + 128] + sbuf[threadIdx.x + 192];
        atomicAdd(&stats[col], s);
    }
    __syncthreads();
    sbuf[threadIdx.x] = q;
    __syncthreads();
    if (threadIdx.x < 64) {
        q = sbuf[threadIdx.x] + sbuf[threadIdx.x + 64] +
            sbuf[threadIdx.x + 128] + sbuf[threadIdx.x + 192];
        atomicAdd(&stats[64 + col], q);
    }
}

// K5: BN normalize + residual + exact GELU, in place on d_out
__global__ __launch_bounds__(256) void k_final(
    float* __restrict__ out, const float* __restrict__ x,
    const float* __restrict__ stats, const float* __restrict__ gamma,
    const float* __restrict__ beta, int total, float invn)
{
    int i = blockIdx.x * 256 + threadIdx.x;
    if (i >= total) return;
    int c = i & 63;
    float mean = stats[c] * invn;
    float var = stats[64 + c] * invn - mean * mean;
    float z = (out[i] - mean) * rsqrtf(var + BN_EPS) * gamma[c] + beta[c] + x[i];
    out[i] = z * 0.5f * (1.f + erff(z * 0.70710678118654752f));
}

extern "C" void kernel_launch(void* const* d_in, const int* in_sizes, int n_in,
                              void* d_out, int out_size, void* d_ws, size_t ws_size,
                              hipStream_t stream)
{
    const float* x     = (const float*)d_in[0];
    const int*   ei    = (const int*)d_in[1];
    const float* eattr = (const float*)d_in[2];
    const float* Wl    = (const float*)d_in[3];
    const float* bl    = (const float*)d_in[4];
    const float* Wr    = (const float*)d_in[5];
    const float* br    = (const float*)d_in[6];
    const float* We    = (const float*)d_in[7];
    const float* att   = (const float*)d_in[8];
    const float* bias  = (const float*)d_in[9];
    const float* gamma = (const float*)d_in[10];
    const float* beta  = (const float*)d_in[11];
    int n = in_sizes[0] / NODE_DIM;
    int E = in_sizes[1] / 2;

    char* ws = (char*)d_ws;
    float*    xr      = (float*)ws;    ws += (size_t)n * NODE_DIM * 4;
    ushort_t* xlbf    = (ushort_t*)ws; ws += (size_t)n * NODE_DIM * 2;
    float*    eattr_s = (float*)ws;    ws += (size_t)E * EDGE_DIM * 4;
    int*      slots   = (int*)ws;      ws += (size_t)E * 4;
    int*      offs    = (int*)ws;      ws += (size_t)n * 4;
    int*      counts  = (int*)ws;      ws += (size_t)n * 4;
    int*      cursors = (int*)ws;      ws += (size_t)n * 4;
    float*    stats   = (float*)ws;    ws += 128 * 4;

    // zero counts + cursors + stats (counts..stats contiguous)
    hipMemsetAsync(counts, 0, (size_t)(2 * n + 128) * 4, stream);

    k_transform<<<512, 256, 0, stream>>>(x, Wl, bl, Wr, br, xlbf, xr, n);
    k_count<<<(E + 255) / 256, 256, 0, stream>>>(ei, counts, E);
    k_scan<<<1, 256, 0, stream>>>(counts, offs, n);
    k_scatter<<<(E + 255) / 256, 256, 0, stream>>>(
        ei, (const float4*)eattr, offs, cursors, slots, (float4*)eattr_s, E);
    k_fused<<<(n + 3) / 4, 256, 0, stream>>>(
        slots, offs, counts, eattr_s, We, att, xlbf, xr, bias,
        (float*)d_out, n);
    k_bnstat<<<256, 256, 0, stream>>>((const float*)d_out, stats, n);
    k_final<<<(n * NODE_DIM + 255) / 256, 256, 0, stream>>>(
        (float*)d_out, x, stats, gamma, beta, n * NODE_DIM, 1.0f / n);
}

// Round 7
// 276.989 us; speedup vs baseline: 1.3845x; 1.3845x over previous
//
#include <hip/hip_runtime.h>
#include <math.h>

#define NODE_DIM 64
#define EDGE_DIM 16
#define CAP 64
#define NEG_SLOPE 0.2f
#define BN_EPS 1e-5f

typedef unsigned short ushort_t;

__device__ __forceinline__ float lrelu(float s) {
    return fmaxf(s, 0.f) + NEG_SLOPE * fminf(s, 0.f);
}
__device__ __forceinline__ ushort_t f2bf(float f) {  // round-to-nearest-even
    unsigned int b = __float_as_uint(f);
    b += 0x7FFFu + ((b >> 16) & 1u);
    return (ushort_t)(b >> 16);
}
__device__ __forceinline__ float bf2f(ushort_t u) {
    return __uint_as_float(((unsigned int)u) << 16);
}

// K1: xr = x@Wr + br (f32) ; xlbf = bf16(x@Wl + bl). One wave per row.
__global__ __launch_bounds__(256) void k_transform(
    const float* __restrict__ x, const float* __restrict__ Wl,
    const float* __restrict__ bl, const float* __restrict__ Wr,
    const float* __restrict__ br, ushort_t* __restrict__ xlbf,
    float* __restrict__ xr, int n)
{
    __shared__ float sWl[NODE_DIM * NODE_DIM];
    __shared__ float sWr[NODE_DIM * NODE_DIM];
    for (int i = threadIdx.x; i < NODE_DIM * NODE_DIM; i += 256) {
        sWl[i] = Wl[i];
        sWr[i] = Wr[i];
    }
    __syncthreads();
    int lane = threadIdx.x & 63;
    int wid = threadIdx.x >> 6;
    for (int row = blockIdx.x * 4 + wid; row < n; row += gridDim.x * 4) {
        float xown = x[(size_t)row * NODE_DIM + lane];
        float al = bl[lane], ar = br[lane];
#pragma unroll
        for (int k = 0; k < NODE_DIM; k++) {
            float xv = __shfl(xown, k, 64);
            al = fmaf(xv, sWl[k * 64 + lane], al);
            ar = fmaf(xv, sWr[k * 64 + lane], ar);
        }
        xlbf[(size_t)row * NODE_DIM + lane] = f2bf(al);
        xr[(size_t)row * NODE_DIM + lane] = ar;
    }
}

// K2: bucket edges by dst; store (src, eid) packed. cursors end as degree.
__global__ __launch_bounds__(256) void k_scatter(
    const int* __restrict__ ei, int* __restrict__ cursors,
    int2* __restrict__ slot2, int E)
{
    int e = blockIdx.x * 256 + threadIdx.x;
    if (e >= E) return;
    int src = ei[e];
    int dst = ei[E + e];
    int pos = atomicAdd(&cursors[dst], 1);
    if (pos < CAP) slot2[(size_t)dst * CAP + pos] = make_int2(src, e);
}

struct Pipe {
    float4 e0, e1, e2, e3;
    ushort_t xu;
};

// K3 (fused): 4 nodes/block, one wave each. ZERO LDS, no __syncthreads.
// lane = channel. Per-edge loop (4-deep pipelined): edge logits via 16-lane
// shuffle reduce, then ONLINE softmax + aggregation entirely in registers.
__global__ __launch_bounds__(256) void k_fused(
    const int2* __restrict__ slot2, const int* __restrict__ cursors,
    const float* __restrict__ eattr, const float* __restrict__ We,
    const float* __restrict__ att, const ushort_t* __restrict__ xlbf,
    const float* __restrict__ xr, const float* __restrict__ bias,
    float* __restrict__ out, int n)
{
    int wid = threadIdx.x >> 6;
    int lane = threadIdx.x & 63;
    int i = blockIdx.x * 4 + wid;
    if (i >= n) return;

    int deg = cursors[i];
    if (deg > CAP) deg = CAP;
    bool act = (lane < deg);

    int2 se = act ? slot2[(size_t)i * CAP + lane] : make_int2(0, 0);
    int se_x = se.x, se_y = se.y;

    // per-lane channel constants
    float xr_c = xr[(size_t)i * NODE_DIM + lane];
    float att_p = att[lane];            // att[h][c] flat == lane
    float att_n = att_p * NEG_SLOPE;
    float we_c[EDGE_DIM];
#pragma unroll
    for (int k = 0; k < EDGE_DIM; k++) we_c[k] = We[k * NODE_DIM + lane];

    // online-softmax state (per lane; uniform within each 16-lane head group)
    float m = -1e30f, ssum = 0.f, acc = 0.f;

    auto LOADP = [&](int T, Pipe& P) {
        int src_t = __builtin_amdgcn_readlane(se_x, T);
        int eid_t = __builtin_amdgcn_readlane(se_y, T);
        const float4* e4 = (const float4*)(eattr + (size_t)eid_t * EDGE_DIM);
        P.e0 = e4[0]; P.e1 = e4[1]; P.e2 = e4[2]; P.e3 = e4[3];
        P.xu = xlbf[(size_t)src_t * NODE_DIM + lane];
    };
    auto COMP = [&](const Pipe& P) {
        float p0 = 0.f, p1 = 0.f;
        p0 = fmaf(P.e0.x, we_c[0], p0);  p1 = fmaf(P.e0.y, we_c[1], p1);
        p0 = fmaf(P.e0.z, we_c[2], p0);  p1 = fmaf(P.e0.w, we_c[3], p1);
        p0 = fmaf(P.e1.x, we_c[4], p0);  p1 = fmaf(P.e1.y, we_c[5], p1);
        p0 = fmaf(P.e1.z, we_c[6], p0);  p1 = fmaf(P.e1.w, we_c[7], p1);
        p0 = fmaf(P.e2.x, we_c[8], p0);  p1 = fmaf(P.e2.y, we_c[9], p1);
        p0 = fmaf(P.e2.z, we_c[10], p0); p1 = fmaf(P.e2.w, we_c[11], p1);
        p0 = fmaf(P.e3.x, we_c[12], p0); p1 = fmaf(P.e3.y, we_c[13], p1);
        p0 = fmaf(P.e3.z, we_c[14], p0); p1 = fmaf(P.e3.w, we_c[15], p1);
        float xu_f = bf2f(P.xu);
        float sv = xu_f + xr_c + (p0 + p1);
        float g = sv * (sv > 0.f ? att_p : att_n);   // lrelu(sv)*att_c
        g += __shfl_xor(g, 1, 64);
        g += __shfl_xor(g, 2, 64);
        g += __shfl_xor(g, 4, 64);
        g += __shfl_xor(g, 8, 64);
        // online softmax update; branch uniform within each 16-lane group
        if (g > m) {
            float r = __expf(m - g);   // first edge: exp(-huge) -> 0
            ssum *= r;
            acc *= r;
            m = g;
        }
        float w = __expf(g - m);
        ssum += w;
        acc = fmaf(w, xu_f, acc);
    };

    // ---- 4-deep software pipeline over edges ----
    if (deg > 0) {
        Pipe PA, PB, PC, PD;
        LOADP(0, PA);
        if (deg > 1) LOADP(1, PB);
        if (deg > 2) LOADP(2, PC);
        int t = 0;
        for (;;) {
            if (t + 3 < deg) LOADP(t + 3, PD);
            COMP(PA); if (++t >= deg) break;
            if (t + 3 < deg) LOADP(t + 3, PA);
            COMP(PB); if (++t >= deg) break;
            if (t + 3 < deg) LOADP(t + 3, PB);
            COMP(PC); if (++t >= deg) break;
            if (t + 3 < deg) LOADP(t + 3, PC);
            COMP(PD); if (++t >= deg) break;
        }
    }

    out[(size_t)i * NODE_DIM + lane] = acc / (ssum + 1e-16f) + bias[lane];
}

// K4: column sums / sumsq for BatchNorm
__global__ __launch_bounds__(256) void k_bnstat(
    const float* __restrict__ out, float* __restrict__ stats, int n)
{
    __shared__ float sbuf[256];
    int col = threadIdx.x & 63;
    int rgrp = threadIdx.x >> 6;
    float s = 0.f, q = 0.f;
    for (int row = blockIdx.x * 4 + rgrp; row < n; row += gridDim.x * 4) {
        float v = out[(size_t)row * 64 + col];
        s += v;
        q = fmaf(v, v, q);
    }
    sbuf[threadIdx.x] = s;
    __syncthreads();
    if (threadIdx.x < 64) {
        s = sbuf[threadIdx.x] + sbuf[threadIdx.x + 64] +
            sbuf[threadIdx.x + 128] + sbuf[threadIdx.x + 192];
        atomicAdd(&stats[col], s);
    }
    __syncthreads();
    sbuf[threadIdx.x] = q;
    __syncthreads();
    if (threadIdx.x < 64) {
        q = sbuf[threadIdx.x] + sbuf[threadIdx.x + 64] +
            sbuf[threadIdx.x + 128] + sbuf[threadIdx.x + 192];
        atomicAdd(&stats[64 + col], q);
    }
}

// K5: BN normalize + residual + exact GELU, in place on d_out
__global__ __launch_bounds__(256) void k_final(
    float* __restrict__ out, const float* __restrict__ x,
    const float* __restrict__ stats, const float* __restrict__ gamma,
    const float* __restrict__ beta, int total, float invn)
{
    int i = blockIdx.x * 256 + threadIdx.x;
    if (i >= total) return;
    int c = i & 63;
    float mean = stats[c] * invn;
    float var = stats[64 + c] * invn - mean * mean;
    float z = (out[i] - mean) * rsqrtf(var + BN_EPS) * gamma[c] + beta[c] + x[i];
    out[i] = z * 0.5f * (1.f + erff(z * 0.70710678118654752f));
}

extern "C" void kernel_launch(void* const* d_in, const int* in_sizes, int n_in,
                              void* d_out, int out_size, void* d_ws, size_t ws_size,
                              hipStream_t stream)
{
    const float* x     = (const float*)d_in[0];
    const int*   ei    = (const int*)d_in[1];
    const float* eattr = (const float*)d_in[2];
    const float* Wl    = (const float*)d_in[3];
    const float* bl    = (const float*)d_in[4];
    const float* Wr    = (const float*)d_in[5];
    const float* br    = (const float*)d_in[6];
    const float* We    = (const float*)d_in[7];
    const float* att   = (const float*)d_in[8];
    const float* bias  = (const float*)d_in[9];
    const float* gamma = (const float*)d_in[10];
    const float* beta  = (const float*)d_in[11];
    int n = in_sizes[0] / NODE_DIM;
    int E = in_sizes[1] / 2;

    char* ws = (char*)d_ws;
    float*    xr     = (float*)ws;    ws += (size_t)n * NODE_DIM * 4;
    ushort_t* xlbf   = (ushort_t*)ws; ws += (size_t)n * NODE_DIM * 2;
    int2*     slot2  = (int2*)ws;     ws += (size_t)n * CAP * 8;
    int*      cursors= (int*)ws;      ws += (size_t)n * 4;
    float*    stats  = (float*)ws;    ws += 128 * 4;

    // zero cursors + stats (contiguous)
    hipMemsetAsync(cursors, 0, (size_t)(n + 128) * 4, stream);

    k_transform<<<512, 256, 0, stream>>>(x, Wl, bl, Wr, br, xlbf, xr, n);
    k_scatter<<<(E + 255) / 256, 256, 0, stream>>>(ei, cursors, slot2, E);
    k_fused<<<(n + 3) / 4, 256, 0, stream>>>(slot2, cursors, eattr, We, att,
                                             xlbf, xr, bias, (float*)d_out, n);
    k_bnstat<<<256, 256, 0, stream>>>((const float*)d_out, stats, n);
    k_final<<<(n * NODE_DIM + 255) / 256, 256, 0, stream>>>(
        (float*)d_out, x, stats, gamma, beta, n * NODE_DIM, 1.0f / n);
}